// Round 1
// baseline (456.079 us; speedup 1.0000x reference)
//
#include <hip/hip_runtime.h>
#include <hip/hip_bf16.h>
#include <math.h>

#define BATCH 32
#define DFEAT 21
#define NPTS 1024
#define KSEL 32
#define NOUT 64

__device__ __forceinline__ unsigned ord32(float f) {
    unsigned u = __float_as_uint(f);
    return ((int)u >= 0) ? (u | 0x80000000u) : ~u;
}
__device__ __forceinline__ float iord32(unsigned u) {
    unsigned s = (u & 0x80000000u) ? (u & 0x7FFFFFFFu) : ~u;
    return __uint_as_float(s);
}

// ---------------------------------------------------------------------------
// Kernel 1: per-row KNN (top-32 of pd = 2*inner - xx_n - xx_m), plus
// sub[b,n,k] = <x_{idx_k}, x_{idx_0}>.
// grid 256 (32 b x 8 chunks), block 1024 (16 waves x 8 rows), dyn LDS 120KB.
// ---------------------------------------------------------------------------
__global__ __launch_bounds__(1024) void knn_kernel(
        const float* __restrict__ x,
        int* __restrict__ idx_ws, float* __restrict__ dist_ws,
        float* __restrict__ sub_ws) {
    extern __shared__ float smem[];
    float* xs  = smem;                       // [21][1024]
    float* xxs = smem + DFEAT * NPTS;        // [1024]
    unsigned long long* cand =
        (unsigned long long*)(smem + DFEAT * NPTS + NPTS);  // [16][256]

    const int tid  = threadIdx.x;
    const int lane = tid & 63;
    const int w    = tid >> 6;
    const int b      = blockIdx.x >> 3;
    const int nchunk = blockIdx.x & 7;

    const float* xb = x + (size_t)b * DFEAT * NPTS;
    for (int i = tid; i < DFEAT * NPTS; i += 1024) xs[i] = xb[i];
    __syncthreads();
    {
        const int m = tid;  // block is exactly 1024 threads
        float s = 0.f;
        #pragma unroll
        for (int d = 0; d < DFEAT; ++d) { float v = xs[d * NPTS + m]; s = fmaf(v, v, s); }
        xxs[m] = s;
    }
    __syncthreads();

    unsigned long long* cw = cand + w * 256;

    for (int r = 0; r < 8; ++r) {
        const int n = nchunk * 128 + w * 8 + r;
        float xn[DFEAT];
        #pragma unroll
        for (int d = 0; d < DFEAT; ++d) xn[d] = xs[d * NPTS + n];
        const float xxn = xxs[n];

        float acc[16];
        #pragma unroll
        for (int i = 0; i < 16; ++i) acc[i] = 0.f;
        #pragma unroll
        for (int d = 0; d < DFEAT; ++d) {
            const float xd = xn[d];
            const float* rowp = xs + d * NPTS;
            #pragma unroll
            for (int i = 0; i < 16; ++i)
                acc[i] = fmaf(rowp[i * 64 + lane], xd, acc[i]);
        }

        unsigned long long keys[16];
        #pragma unroll
        for (int i = 0; i < 16; ++i) {
            const int m = i * 64 + lane;
            const float pd = (2.f * acc[i] - xxn) - xxs[m];
            keys[i] = ((unsigned long long)ord32(pd) << 32) | (unsigned)(~m);
        }

        // threshold = 32nd-largest of the 64 lane-maxima (bitonic sort)
        unsigned long long lmax = keys[0];
        #pragma unroll
        for (int i = 1; i < 16; ++i) lmax = keys[i] > lmax ? keys[i] : lmax;
        unsigned long long v = lmax;
        #pragma unroll
        for (int kk = 2; kk <= 64; kk <<= 1) {
            #pragma unroll
            for (int j = kk >> 1; j >= 1; j >>= 1) {
                unsigned long long o = __shfl_xor(v, j);
                const bool up      = ((lane & kk) == 0);
                const bool upper   = ((lane & j) != 0);
                const bool takeMax = (upper == up);
                const bool sw      = takeMax ? (o > v) : (o < v);
                v = sw ? o : v;
            }
        }
        const unsigned long long T = __shfl(v, 32);

        int c = 0;
        #pragma unroll
        for (int i = 0; i < 16; ++i) c += (keys[i] >= T) ? 1 : 0;
        int s = c;
        #pragma unroll
        for (int off = 1; off < 64; off <<= 1) {
            int t2 = __shfl_up(s, off);
            if (lane >= off) s += t2;
        }
        const int base = s - c;
        const int Ctot = __shfl(s, 63);

        unsigned long long mywin = 0ULL;
        if (Ctot <= 256) {
            int p = base;
            #pragma unroll
            for (int i = 0; i < 16; ++i) {
                if (keys[i] >= T) { if (p < 256) cw[p] = keys[i]; ++p; }
            }
            __asm__ volatile("s_waitcnt lgkmcnt(0)" ::: "memory");
            unsigned long long cr[4];
            #pragma unroll
            for (int i = 0; i < 4; ++i) {
                const int ci = lane + i * 64;
                cr[i] = (ci < Ctot) ? cw[ci] : 0ULL;
            }
            for (int it = 0; it < 32; ++it) {
                unsigned long long a01 = cr[0] > cr[1] ? cr[0] : cr[1];
                unsigned long long a23 = cr[2] > cr[3] ? cr[2] : cr[3];
                unsigned long long lm = a01 > a23 ? a01 : a23;
                #pragma unroll
                for (int off = 32; off >= 1; off >>= 1) {
                    unsigned long long o = __shfl_xor(lm, off);
                    lm = o > lm ? o : lm;
                }
                mywin = (lane == it) ? lm : mywin;
                #pragma unroll
                for (int i = 0; i < 4; ++i) cr[i] = (cr[i] == lm) ? 0ULL : cr[i];
            }
        } else {
            // exact slow fallback (statistically never taken)
            for (int it = 0; it < 32; ++it) {
                unsigned long long lm = keys[0];
                #pragma unroll
                for (int i = 1; i < 16; ++i) lm = keys[i] > lm ? keys[i] : lm;
                #pragma unroll
                for (int off = 32; off >= 1; off >>= 1) {
                    unsigned long long o = __shfl_xor(lm, off);
                    lm = o > lm ? o : lm;
                }
                mywin = (lane == it) ? lm : mywin;
                #pragma unroll
                for (int i = 0; i < 16; ++i) keys[i] = (keys[i] == lm) ? 0ULL : keys[i];
            }
        }

        const int   m_sel = (int)(~((unsigned)mywin));
        const float pdv   = iord32((unsigned)(mywin >> 32));
        const int   m0    = __shfl(m_sel, 0);
        if (lane < KSEL) {
            const size_t obase = ((size_t)(b * NPTS + n)) * KSEL + lane;
            idx_ws[obase]  = m_sel;
            dist_ws[obase] = -pdv;
            float sv = 0.f;
            #pragma unroll
            for (int d = 0; d < DFEAT; ++d)
                sv = fmaf(xs[d * NPTS + m_sel], xs[d * NPTS + m0], sv);
            sub_ws[obase] = sv;
        }
    }
}

// ---------------------------------------------------------------------------
// Kernel 2: norm2[b,k,j] = sum_n (sub[n,k]*sub[n,j])^2 ; store 1/max(sqrt,1e-12)
// grid 32 (per b), block 1024 (k = t/32, j = t%32)
// ---------------------------------------------------------------------------
__global__ __launch_bounds__(1024) void norm_kernel(
        const float* __restrict__ sub_ws, float* __restrict__ recip_ws) {
    const int b = blockIdx.x;
    const int k = threadIdx.x >> 5;
    const int j = threadIdx.x & 31;
    const float* sb = sub_ws + (size_t)b * NPTS * KSEL;
    float acc = 0.f;
    #pragma unroll 4
    for (int n = 0; n < NPTS; ++n) {
        const float a = sb[n * KSEL + k];
        const float c = sb[n * KSEL + j];
        const float p = a * c;
        acc = fmaf(p, p, acc);
    }
    const float nr = sqrtf(acc);
    recip_ws[(size_t)b * NPTS + threadIdx.x] = 1.0f / fmaxf(nr, 1e-12f);
}

// ---------------------------------------------------------------------------
// Kernel 3: gm_red[b,n,k] = sub[n,k] * sum_c (w_gm[c]*sub[n,c]) * recip[k,c]
// + f64 partial sums for BN1 (raw dist) and BN2 (gm_red).
// grid 4096 (8 rows each), block 256 (r = t/32, k = t%32)
// ---------------------------------------------------------------------------
__global__ __launch_bounds__(256) void gmred_kernel(
        const float* __restrict__ sub_ws, const float* __restrict__ dist_ws,
        const float* __restrict__ recip_ws, const float* __restrict__ w_gm,
        float* __restrict__ gmred_ws, double* __restrict__ part12) {
    __shared__ float recipS[32 * 33];
    __shared__ float subS[8 * 32];
    __shared__ float subWS[8 * 32];
    __shared__ double redS[4][4];

    const int tid = threadIdx.x;
    const int b   = blockIdx.x >> 7;
    const int n0  = (blockIdx.x & 127) * 8;

    for (int i = tid; i < 1024; i += 256)
        recipS[(i >> 5) * 33 + (i & 31)] = recip_ws[(size_t)b * NPTS + i];
    {
        const float sv = sub_ws[((size_t)(b * NPTS + n0)) * KSEL + tid];
        subS[tid]  = sv;
        subWS[tid] = sv * w_gm[tid & 31];
    }
    __syncthreads();

    const int r = tid >> 5, k = tid & 31;
    float s = 0.f;
    #pragma unroll
    for (int c = 0; c < 32; ++c)
        s = fmaf(subWS[r * 32 + c], recipS[k * 33 + c], s);
    const float g = subS[r * 32 + k] * s;
    const size_t row = (size_t)(b * NPTS + n0 + r);
    gmred_ws[row * KSEL + k] = g;
    const float dv = dist_ws[row * KSEL + k];

    double s1 = (double)dv, s2 = (double)dv * (double)dv;
    double s3 = (double)g,  s4 = (double)g * (double)g;
    #pragma unroll
    for (int off = 32; off >= 1; off >>= 1) {
        s1 += __shfl_xor(s1, off);
        s2 += __shfl_xor(s2, off);
        s3 += __shfl_xor(s3, off);
        s4 += __shfl_xor(s4, off);
    }
    if ((tid & 63) == 0) {
        const int wv = tid >> 6;
        redS[wv][0] = s1; redS[wv][1] = s2; redS[wv][2] = s3; redS[wv][3] = s4;
    }
    __syncthreads();
    if (tid == 0) {
        double a0 = 0, a1 = 0, a2 = 0, a3 = 0;
        #pragma unroll
        for (int wv = 0; wv < 4; ++wv) {
            a0 += redS[wv][0]; a1 += redS[wv][1]; a2 += redS[wv][2]; a3 += redS[wv][3];
        }
        part12[(size_t)blockIdx.x * 4 + 0] = a0;
        part12[(size_t)blockIdx.x * 4 + 1] = a1;
        part12[(size_t)blockIdx.x * 4 + 2] = a2;
        part12[(size_t)blockIdx.x * 4 + 3] = a3;
    }
}

// ---------------------------------------------------------------------------
// Kernel 4: uc[b,n,o] = sum_d w_up[o,d] * x[b,d,n]
// grid 2048 (16 n each), block 256 (o = t%64, group = t/64)
// ---------------------------------------------------------------------------
__global__ __launch_bounds__(256) void uc_kernel(
        const float* __restrict__ x, const float* __restrict__ w_up,
        float* __restrict__ uc_ws) {
    __shared__ float wS[NOUT * DFEAT];
    __shared__ float xS[DFEAT * 16];
    const int tid = threadIdx.x;
    const int b  = blockIdx.x >> 6;
    const int n0 = (blockIdx.x & 63) * 16;
    for (int i = tid; i < NOUT * DFEAT; i += 256) wS[i] = w_up[i];
    for (int i = tid; i < DFEAT * 16; i += 256) {
        const int d = i >> 4, c = i & 15;
        xS[i] = x[((size_t)b * DFEAT + d) * NPTS + n0 + c];
    }
    __syncthreads();
    const int o = tid & 63, g = tid >> 6;
    #pragma unroll
    for (int nn = g; nn < 16; nn += 4) {
        float a = 0.f;
        #pragma unroll
        for (int d = 0; d < DFEAT; ++d)
            a = fmaf(wS[o * DFEAT + d], xS[d * 16 + nn], a);
        uc_ws[((size_t)(b * NPTS) + n0 + nn) * NOUT + o] = a;
    }
}

// ---------------------------------------------------------------------------
// Kernel 5: reduce BN1/BN2 partials -> folded scale/offset consts
// ---------------------------------------------------------------------------
__global__ __launch_bounds__(256) void reduce12_kernel(
        const double* __restrict__ part12, int nblocks,
        const float* __restrict__ w_dist,
        const float* __restrict__ g1, const float* __restrict__ b1,
        const float* __restrict__ g2, const float* __restrict__ b2,
        float* __restrict__ consts) {
    __shared__ double S[256][4];
    const int t = threadIdx.x;
    double a0 = 0, a1 = 0, a2 = 0, a3 = 0;
    for (int i = t; i < nblocks; i += 256) {
        a0 += part12[(size_t)i * 4 + 0];
        a1 += part12[(size_t)i * 4 + 1];
        a2 += part12[(size_t)i * 4 + 2];
        a3 += part12[(size_t)i * 4 + 3];
    }
    S[t][0] = a0; S[t][1] = a1; S[t][2] = a2; S[t][3] = a3;
    __syncthreads();
    for (int off = 128; off >= 1; off >>= 1) {
        if (t < off) {
            S[t][0] += S[t + off][0]; S[t][1] += S[t + off][1];
            S[t][2] += S[t + off][2]; S[t][3] += S[t + off][3];
        }
        __syncthreads();
    }
    if (t == 0) {
        const double M = (double)BATCH * NPTS * KSEL;
        const double E1 = S[0][0] / M, E2 = S[0][1] / M;
        const double wd = (double)w_dist[0];
        const double mean1 = wd * E1;
        const double var1  = wd * wd * (E2 - E1 * E1);
        const double istd1 = 1.0 / sqrt(var1 + 1e-5);
        consts[0] = (float)(wd * istd1 * (double)g1[0]);
        consts[1] = (float)((double)b1[0] - mean1 * istd1 * (double)g1[0]);
        const double F1 = S[0][2] / M, F2 = S[0][3] / M;
        const double var2  = F2 - F1 * F1;
        const double istd2 = 1.0 / sqrt(var2 + 1e-5);
        consts[2] = (float)(istd2 * (double)g2[0]);
        consts[3] = (float)((double)b2[0] - F1 * istd2 * (double)g2[0]);
    }
}

// ---------------------------------------------------------------------------
// Kernel 6: gate = sigmoid(BN1(dist*wd)) * sigmoid(BN2(gm_red)); BN3 partials
// grid 512 (64 rows each), block 256 (4 waves x 16 rows; lane = channel o)
// ---------------------------------------------------------------------------
__global__ __launch_bounds__(256) void gate_stats_kernel(
        const float* __restrict__ dist_ws, const float* __restrict__ gmred_ws,
        const int* __restrict__ idx_ws, const float* __restrict__ uc_ws,
        const float* __restrict__ consts,
        float* __restrict__ gate_ws, double* __restrict__ part3) {
    const int tid = threadIdx.x, lane = tid & 63, w = tid >> 6;
    const int row0 = blockIdx.x * 64;
    const float A1 = consts[0], C1 = consts[1], A2 = consts[2], C2 = consts[3];
    double sum = 0.0, ssq = 0.0;
    for (int rr = 0; rr < 16; ++rr) {
        const int row = row0 + w * 16 + rr;
        const int b = row >> 10;
        float gate = 0.f; int jj = 0;
        if (lane < KSEL) {
            const size_t rbase = (size_t)row * KSEL + lane;
            const float dv = dist_ws[rbase];
            const float gv = gmred_ws[rbase];
            jj = idx_ws[rbase];
            const float z1 = fmaf(dv, A1, C1);
            const float z2 = fmaf(gv, A2, C2);
            const float w1 = 1.f / (1.f + __expf(-z1));
            const float w2 = 1.f / (1.f + __expf(-z2));
            gate = w1 * w2;
            gate_ws[rbase] = gate;
        }
        const float ucr = uc_ws[(size_t)row * NOUT + lane];
        const float* ucb = uc_ws + ((size_t)(b * NPTS)) * NOUT;
        #pragma unroll 8
        for (int k = 0; k < KSEL; ++k) {
            const float gk = __shfl(gate, k);
            const int   jk = __shfl(jj, k);
            const float ucn = ucb[(size_t)jk * NOUT + lane];
            const float up  = fmaf(gk, ucn - ucr, ucr);
            sum += (double)up;
            ssq = fma((double)up, (double)up, ssq);
        }
    }
    __shared__ double p3[4][64][2];
    p3[w][lane][0] = sum; p3[w][lane][1] = ssq;
    __syncthreads();
    if (w == 0) {
        const double s = p3[0][lane][0] + p3[1][lane][0] + p3[2][lane][0] + p3[3][lane][0];
        const double q = p3[0][lane][1] + p3[1][lane][1] + p3[2][lane][1] + p3[3][lane][1];
        part3[((size_t)blockIdx.x * 64 + lane) * 2 + 0] = s;
        part3[((size_t)blockIdx.x * 64 + lane) * 2 + 1] = q;
    }
}

// ---------------------------------------------------------------------------
// Kernel 7: reduce BN3 partials -> per-channel A/C
// ---------------------------------------------------------------------------
__global__ __launch_bounds__(256) void reduce3_kernel(
        const double* __restrict__ part3,
        const float* __restrict__ g3, const float* __restrict__ b3,
        float* __restrict__ consts3) {
    const int t = threadIdx.x;
    const int o = t & 63, gq = t >> 6;
    double s = 0, q = 0;
    for (int i = gq; i < 512; i += 4) {
        s += part3[((size_t)i * 64 + o) * 2 + 0];
        q += part3[((size_t)i * 64 + o) * 2 + 1];
    }
    __shared__ double S[4][64][2];
    S[gq][o][0] = s; S[gq][o][1] = q;
    __syncthreads();
    if (t < 64) {
        const double ss = S[0][o][0] + S[1][o][0] + S[2][o][0] + S[3][o][0];
        const double qq = S[0][o][1] + S[1][o][1] + S[2][o][1] + S[3][o][1];
        const double M = (double)BATCH * NPTS * KSEL;
        const double mean = ss / M;
        const double var  = qq / M - mean * mean;
        const double istd = 1.0 / sqrt(var + 1e-5);
        consts3[o]      = (float)(istd * (double)g3[o]);
        consts3[64 + o] = (float)((double)b3[o] - mean * istd * (double)g3[o]);
    }
}

// ---------------------------------------------------------------------------
// Kernel 8: out[b,o,n] = mean_k lrelu(up*A[o]+C[o])
// ---------------------------------------------------------------------------
__global__ __launch_bounds__(256) void final_kernel(
        const float* __restrict__ gate_ws, const int* __restrict__ idx_ws,
        const float* __restrict__ uc_ws, const float* __restrict__ consts3,
        float* __restrict__ out) {
    const int tid = threadIdx.x, lane = tid & 63, w = tid >> 6;
    const int row0 = blockIdx.x * 64;
    const float A = consts3[lane], C = consts3[64 + lane];
    for (int rr = 0; rr < 16; ++rr) {
        const int row = row0 + w * 16 + rr;
        const int b = row >> 10, n = row & 1023;
        float gate = 0.f; int jj = 0;
        if (lane < KSEL) {
            gate = gate_ws[(size_t)row * KSEL + lane];
            jj   = idx_ws[(size_t)row * KSEL + lane];
        }
        const float ucr = uc_ws[(size_t)row * NOUT + lane];
        const float* ucb = uc_ws + ((size_t)(b * NPTS)) * NOUT;
        float acc = 0.f;
        #pragma unroll 8
        for (int k = 0; k < KSEL; ++k) {
            const float gk = __shfl(gate, k);
            const int   jk = __shfl(jj, k);
            const float ucn = ucb[(size_t)jk * NOUT + lane];
            const float up  = fmaf(gk, ucn - ucr, ucr);
            float z = fmaf(up, A, C);
            z = (z >= 0.f) ? z : 0.02f * z;
            acc += z;
        }
        out[((size_t)b * NOUT + lane) * NPTS + n] = acc * (1.f / 32.f);
    }
}

// ---------------------------------------------------------------------------
extern "C" void kernel_launch(void* const* d_in, const int* in_sizes, int n_in,
                              void* d_out, int out_size, void* d_ws, size_t ws_size,
                              hipStream_t stream) {
    const float* x      = (const float*)d_in[0];
    const float* w_dist = (const float*)d_in[2];
    const float* g1     = (const float*)d_in[3];
    const float* b1     = (const float*)d_in[4];
    const float* w_gm   = (const float*)d_in[5];
    const float* g2     = (const float*)d_in[6];
    const float* b2     = (const float*)d_in[7];
    const float* w_up   = (const float*)d_in[8];
    const float* g3     = (const float*)d_in[9];
    const float* b3     = (const float*)d_in[10];
    float* out = (float*)d_out;

    char* ws = (char*)d_ws;
    int*    idx_ws   = (int*)(ws + 0);
    float*  dist_ws  = (float*)(ws + ((size_t)4 << 20));
    float*  sub_ws   = (float*)(ws + ((size_t)8 << 20));
    float*  gmred_ws = (float*)(ws + ((size_t)12 << 20));
    float*  gate_ws  = (float*)(ws + ((size_t)16 << 20));
    float*  uc_ws    = (float*)(ws + ((size_t)20 << 20));
    float*  recip_ws = (float*)(ws + ((size_t)28 << 20));
    double* part12   = (double*)(ws + ((size_t)28 << 20) + 0x20000);
    double* part3    = (double*)(ws + ((size_t)28 << 20) + 0x40000);
    float*  consts   = (float*)(ws + ((size_t)28 << 20) + 0xC0000);
    float*  consts3  = consts + 4;

    knn_kernel<<<dim3(256), dim3(1024), 120 * 1024, stream>>>(x, idx_ws, dist_ws, sub_ws);
    norm_kernel<<<dim3(32), dim3(1024), 0, stream>>>(sub_ws, recip_ws);
    gmred_kernel<<<dim3(4096), dim3(256), 0, stream>>>(sub_ws, dist_ws, recip_ws, w_gm,
                                                       gmred_ws, part12);
    uc_kernel<<<dim3(2048), dim3(256), 0, stream>>>(x, w_up, uc_ws);
    reduce12_kernel<<<dim3(1), dim3(256), 0, stream>>>(part12, 4096, w_dist, g1, b1, g2, b2,
                                                       consts);
    gate_stats_kernel<<<dim3(512), dim3(256), 0, stream>>>(dist_ws, gmred_ws, idx_ws, uc_ws,
                                                           consts, gate_ws, part3);
    reduce3_kernel<<<dim3(1), dim3(256), 0, stream>>>(part3, g3, b3, consts3);
    final_kernel<<<dim3(512), dim3(256), 0, stream>>>(gate_ws, idx_ws, uc_ws, consts3, out);
}